// Round 5
// baseline (346.428 us; speedup 1.0000x reference)
//
#include <hip/hip_runtime.h>

// HarmonicFullyConnectedTensorProduct, lmax=2, MUL=64, B=1024, 11 paths.
// out[z,w,k] += sum_{u,v,m,n} x1[z,u,m] x2[z,v,n] W[p,w,u,v] C_p[m,n,k]
//
// Round 5: LDS-instruction diet.
//  - T-form lane = (zslot, v-octet): x2[8v] in regs, ONE ds_write_b128 per k,
//    c1 gather serves 8 z per instruction (was serial per-z broadcast).
//  - c1 stored bf16 in LDS (z-stride padded: +4dw mod 32 -> conflict-free).
//  - ZT=32, wave = (w-pair, col-half): B-frags read 2x (was 4x).
//  - sc1 built per 8-u half; LDS <= 49.7 KB -> 3 blocks/CU.

#define NTHREADS 256
#define SMEM_BYTES 49920

typedef __attribute__((ext_vector_type(4))) float f32x4;
typedef __attribute__((ext_vector_type(8))) short s16x8;

__device__ __forceinline__ unsigned short f2bf(float x) {
    union { float f; unsigned u; } v; v.f = x;
    unsigned r = v.u + 0x7fffu + ((v.u >> 16) & 1u);   // RNE
    return (unsigned short)(r >> 16);
}
__device__ __forceinline__ float bf2f(unsigned short h) {
    union { unsigned u; float f; } v; v.u = ((unsigned)h) << 16;
    return v.f;
}

// ---------------- prep: W -> bf16, [p][u][w][v] ----------------

__global__ __launch_bounds__(NTHREADS) void prep_w(const float* __restrict__ W,
                                                   unsigned short* __restrict__ Wb)
{
    int id = blockIdx.x * NTHREADS + threadIdx.x;   // (p,u,w,v4): 11*64*64*16
    int v4 = (id & 15) << 2;
    int w  = (id >> 4) & 63;
    int u  = (id >> 10) & 63;
    int p  = id >> 16;
    float4 f = *(const float4*)(W + (((size_t)p * 64 + w) * 64 + u) * 64 + v4);
    ushort4 h;
    h.x = f2bf(f.x); h.y = f2bf(f.y); h.z = f2bf(f.z); h.w = f2bf(f.w);
    *(ushort4*)(Wb + (((size_t)p * 64 + u) * 64 + w) * 64 + v4) = h;
}

// ---------------- main ----------------

struct KArgs {
    const float*          x1[3];
    const float*          x2[3];
    const unsigned short* Wb;
    const float*          C[11];
    float*                out;
};

// ZT=32 z-rows per block. UC u per block (USPLIT=64/UC blocks over u).
// S1b = KN padded to multiple of 8 (bf16 b128 read granularity).
template <int M1, int N1, int K1, int KOFF, int UC, int S1b>
__device__ __forceinline__ void run_path(const float* __restrict__ x1g,
                                         const float* __restrict__ x2g,
                                         const unsigned short* __restrict__ Wbp,
                                         const float* __restrict__ Cg,
                                         float* __restrict__ outg, int local,
                                         char* __restrict__ smem)
{
    constexpr int USPLIT = 64 / UC;
    constexpr int KN  = K1 * N1;
    constexpr int NB  = S1b / 8;          // b128 reads per (z,u) c1 slab
    constexpr int C1Z = 8 * S1b + 8;      // per-z stride (bf16): +8 => +4dw mod 32

    unsigned short* sW  = (unsigned short*)smem;          // [64][72]
    unsigned short* sT  = sW + 64 * 72;                   // [32*K1][72]
    unsigned short* sc1 = sT + 32 * K1 * 72;              // [32][C1Z]
    float*          sC  = (float*)(sc1 + 32 * C1Z);       // [M1*N1*K1]

    const int t = threadIdx.x, lane = t & 63, wave = t >> 6;
    const int ln = lane & 15, q = lane >> 4;
    const int zslot = lane >> 3, voct = lane & 7;
    const int zl = wave * 8 + zslot;            // local z 0..31
    const int ztile = local / USPLIT;
    const int usub  = local % USPLIT;
    const int z0 = ztile * 32;
    const int u0 = usub * UC;
    const int wp = wave >> 1, ch = wave & 1;

    for (int i = t; i < M1 * N1 * K1; i += NTHREADS) sC[i] = Cg[i];

    // x2 for this lane's 8 v values (reused across all u)
    float xr[8][N1];
#pragma unroll
    for (int j = 0; j < 8; ++j) {
        const float* xp = x2g + ((size_t)(z0 + zl) * 64 + voct * 8 + j) * N1;
#pragma unroll
        for (int n = 0; n < N1; ++n) xr[j][n] = xp[n];
    }

    f32x4 acc[2][K1];
#pragma unroll
    for (int wt = 0; wt < 2; ++wt)
#pragma unroll
        for (int c = 0; c < K1; ++c) acc[wt][c] = (f32x4){0.f, 0.f, 0.f, 0.f};

    __syncthreads();

#pragma unroll 1
    for (int half = 0; half < UC / 8; ++half) {
        const int ub = u0 + half * 8;

        // ---- build sc1 (bf16) for 8 u: sc1[z][uu*S1b + k*N1+n]
        for (int i = t; i < 32 * 8 * KN; i += NTHREADS) {
            int z  = i / (8 * KN);
            int r  = i - z * (8 * KN);
            int uu = r / KN;
            int j  = r - uu * KN;
            int k  = j / N1, n = j - k * N1;
            const float* x1r = x1g + ((size_t)(z0 + z) * 64 + ub + uu) * M1;
            float s = 0.f;
#pragma unroll
            for (int m = 0; m < M1; ++m) s += x1r[m] * sC[(m * N1 + n) * K1 + k];
            sc1[z * C1Z + uu * S1b + j] = f2bf(s);
        }
        __syncthreads();

#pragma unroll 1
        for (int uu = 0; uu < 8; ++uu) {
            const int u = ub + uu;
            // W slab loads issued early, stored to LDS after T-form
            const unsigned short* wsrc = Wbp + (size_t)u * 4096;
            s16x8 w0 = *(const s16x8*)(wsrc + t * 8);
            s16x8 w1 = *(const s16x8*)(wsrc + 2048 + t * 8);

            // ---- T-form: lane covers (z=zl, v = voct*8..+7), b128 write per k
            {
                const unsigned short* cp = sc1 + zl * C1Z + uu * S1b;
                s16x8 hv[NB];
#pragma unroll
                for (int b = 0; b < NB; ++b) hv[b] = *(const s16x8*)(cp + b * 8);
                float c1v[KN];
#pragma unroll
                for (int j = 0; j < KN; ++j)
                    c1v[j] = bf2f((unsigned short)hv[j >> 3][j & 7]);
#pragma unroll
                for (int k = 0; k < K1; ++k) {
                    unsigned d[4];
#pragma unroll
                    for (int jj = 0; jj < 4; ++jj) {
                        float s0 = 0.f, s1 = 0.f;
#pragma unroll
                        for (int n = 0; n < N1; ++n) {
                            s0 += xr[jj * 2 + 0][n] * c1v[k * N1 + n];
                            s1 += xr[jj * 2 + 1][n] * c1v[k * N1 + n];
                        }
                        d[jj] = (unsigned)f2bf(s0) | ((unsigned)f2bf(s1) << 16);
                    }
                    *(uint4*)&sT[(zl * K1 + k) * 72 + voct * 8] =
                        make_uint4(d[0], d[1], d[2], d[3]);
                }
            }
            // store W regs: rows t>>3 and 32+(t>>3)
            *(s16x8*)&sW[(t >> 3) * 72 + (t & 7) * 8] = w0;
            *(s16x8*)&sW[(32 + (t >> 3)) * 72 + (t & 7) * 8] = w1;
            __syncthreads();

            // ---- MFMA: wave = (wp: w-pair, ch: col-half), K=64 (v) per u
#pragma unroll
            for (int s2 = 0; s2 < 2; ++s2) {
                s16x8 af[2];
#pragma unroll
                for (int wt = 0; wt < 2; ++wt)
                    af[wt] = *(const s16x8*)
                        &sW[((wp * 2 + wt) * 16 + ln) * 72 + s2 * 32 + q * 8];
#pragma unroll
                for (int c = 0; c < K1; ++c) {
                    s16x8 bf = *(const s16x8*)
                        &sT[((ch * K1 + c) * 16 + ln) * 72 + s2 * 32 + q * 8];
#pragma unroll
                    for (int wt = 0; wt < 2; ++wt)
                        acc[wt][c] = __builtin_amdgcn_mfma_f32_16x16x32_bf16(
                            af[wt], bf, acc[wt][c], 0, 0, 0);
                }
            }
            __syncthreads();
        }
    }

    // ---- epilogue: row = w = (wp*2+wt)*16+q*4+r, col = (ch*K1+c)*16+ln
#pragma unroll
    for (int wt = 0; wt < 2; ++wt) {
#pragma unroll
        for (int c = 0; c < K1; ++c) {
            const int col = (ch * K1 + c) * 16 + ln;
            const int z = col / K1, k = col - z * K1;
            float* op = outg + (size_t)(z0 + z) * 576 + KOFF + k;
#pragma unroll
            for (int r = 0; r < 4; ++r)
                atomicAdd(op + ((wp * 2 + wt) * 16 + q * 4 + r) * 9, acc[wt][c][r]);
        }
    }
}

__global__ __launch_bounds__(NTHREADS, 3) void tp_main(KArgs a)
{
    __shared__ __align__(16) char smem[SMEM_BYTES];

    const int bid = blockIdx.x;
    // heavy-first dispatch order: p2,p10,p5,p7 (K1=5), p1,p6,p8,p3 (K1=3), p9,p4,p0
    const int starts[12] = {0, 128, 256, 384, 512, 640, 768, 896, 1024, 1280, 1536, 1792};
    int idx = 0;
#pragma unroll
    for (int i = 1; i < 12; ++i) idx += (bid >= starts[i]) ? 1 : 0;
    const int local = bid - starts[idx];

    switch (idx) {               //  M1 N1 K1 KOFF UC S1b      x1    x2        C
        case 0:  run_path<1,5,5,4,16,32>(a.x1[0], a.x2[2], a.Wb + (size_t) 2*262144, a.C[2],  a.out, local, smem); break;
        case 1:  run_path<5,5,5,4,16,32>(a.x1[2], a.x2[2], a.Wb + (size_t)10*262144, a.C[10], a.out, local, smem); break;
        case 2:  run_path<3,3,5,4,16,16>(a.x1[1], a.x2[1], a.Wb + (size_t) 5*262144, a.C[5],  a.out, local, smem); break;
        case 3:  run_path<5,1,5,4,16, 8>(a.x1[2], a.x2[0], a.Wb + (size_t) 7*262144, a.C[7],  a.out, local, smem); break;
        case 4:  run_path<1,3,3,1,16,16>(a.x1[0], a.x2[1], a.Wb + (size_t) 1*262144, a.C[1],  a.out, local, smem); break;
        case 5:  run_path<3,5,3,1,16,16>(a.x1[1], a.x2[2], a.Wb + (size_t) 6*262144, a.C[6],  a.out, local, smem); break;
        case 6:  run_path<5,3,3,1,16,16>(a.x1[2], a.x2[1], a.Wb + (size_t) 8*262144, a.C[8],  a.out, local, smem); break;
        case 7:  run_path<3,1,3,1,16, 8>(a.x1[1], a.x2[0], a.Wb + (size_t) 3*262144, a.C[3],  a.out, local, smem); break;
        case 8:  run_path<5,5,1,0, 8, 8>(a.x1[2], a.x2[2], a.Wb + (size_t) 9*262144, a.C[9],  a.out, local, smem); break;
        case 9:  run_path<3,3,1,0, 8, 8>(a.x1[1], a.x2[1], a.Wb + (size_t) 4*262144, a.C[4],  a.out, local, smem); break;
        case 10: run_path<1,1,1,0, 8, 8>(a.x1[0], a.x2[0], a.Wb + (size_t) 0*262144, a.C[0],  a.out, local, smem); break;
        default: break;
    }
}

// ---------------- launch ----------------

extern "C" void kernel_launch(void* const* d_in, const int* in_sizes, int n_in,
                              void* d_out, int out_size, void* d_ws, size_t ws_size,
                              hipStream_t stream)
{
    unsigned short* Wb = (unsigned short*)d_ws;   // 5.77 MB

    KArgs a;
    // dict order: x1_l0, x2_l0, x1_l1, x2_l1, x1_l2, x2_l2, W, C_0..C_10
    a.x1[0] = (const float*)d_in[0];
    a.x2[0] = (const float*)d_in[1];
    a.x1[1] = (const float*)d_in[2];
    a.x2[1] = (const float*)d_in[3];
    a.x1[2] = (const float*)d_in[4];
    a.x2[2] = (const float*)d_in[5];
    a.Wb = Wb;
    for (int p = 0; p < 11; ++p) a.C[p] = (const float*)d_in[7 + p];
    a.out = (float*)d_out;

    prep_w<<<dim3(720896 / NTHREADS), NTHREADS, 0, stream>>>((const float*)d_in[6], Wb);
    hipMemsetAsync(d_out, 0, (size_t)out_size * sizeof(float), stream);
    tp_main<<<dim3(1792), NTHREADS, 0, stream>>>(a);
}